// Round 7
// baseline (533.218 us; speedup 1.0000x reference)
//
#include <hip/hip_runtime.h>
#include <cstdint>
#include <cstddef>

// Problem constants (B=4, T=2048, C=1024, H=16, S=64)
#define TT 2048
#define CC 1024
#define HH 16
#define SS 64
#define MROWS 8192  // B*T
#define KVRN 3072   // fused k|v|r width
#define NCH 32      // WKV chunks per sequence
#define LCH 64      // steps per chunk (TT/NCH)

using short8 = __attribute__((ext_vector_type(8))) short;
using f32x4  = __attribute__((ext_vector_type(4))) float;

__device__ __forceinline__ float b2f(unsigned short u) {
  union { unsigned int i; float f; } c; c.i = ((unsigned int)u) << 16; return c.f;
}
__device__ __forceinline__ unsigned short f2b(float f) {
  union { float f; unsigned int i; } c; c.f = f;
  unsigned int r = c.i + 0x7fffu + ((c.i >> 16) & 1u);  // RNE; inputs finite
  return (unsigned short)(r >> 16);
}

// async global->LDS, 16 bytes per lane (LDS dst = wave-uniform base + lane*16; global per-lane)
typedef const __attribute__((address_space(1))) unsigned int* gas_ptr;
typedef __attribute__((address_space(3))) unsigned int* las_ptr;
__device__ __forceinline__ void gl_lds16(const unsigned short* g, unsigned short* l) {
  __builtin_amdgcn_global_load_lds((gas_ptr)g, (las_ptr)l, 16, 0, 0);
}

// ---------------- fused: all weights fp32->bf16 + LN1 + x2:=x seed, one launch ----------
// blocks [0,12288): cvt; blocks [12288,20480): LN1 row (blockIdx-12288)
__global__ __launch_bounds__(256) void cvt_ln_kernel(const float* __restrict__ Wk,
                                                     const float* __restrict__ Wv,
                                                     const float* __restrict__ Wr,
                                                     const float* __restrict__ Wo,
                                                     const float* __restrict__ Wffk,
                                                     const float* __restrict__ Wffv,
                                                     unsigned short* __restrict__ dst,
                                                     const float* __restrict__ x,
                                                     const float* __restrict__ g,
                                                     const float* __restrict__ bta,
                                                     unsigned short* __restrict__ xlo,
                                                     float* __restrict__ x2o) {
  const size_t M1 = 1048576;
  const int tid = threadIdx.x;
  if (blockIdx.x < 12288) {
    size_t i = ((size_t)blockIdx.x * 256 + tid) * 4;
    const float* src; size_t off;
    if      (i <  1 * M1) { src = Wk;   off = 0;      }
    else if (i <  2 * M1) { src = Wv;   off = 1 * M1; }
    else if (i <  3 * M1) { src = Wr;   off = 2 * M1; }
    else if (i <  4 * M1) { src = Wo;   off = 3 * M1; }
    else if (i <  8 * M1) { src = Wffk; off = 4 * M1; }
    else                  { src = Wffv; off = 8 * M1; }
    float4 v = *(const float4*)(src + (i - off));
    *(ushort4*)(dst + i) = make_ushort4(f2b(v.x), f2b(v.y), f2b(v.z), f2b(v.w));
    return;
  }
  const int row = blockIdx.x - 12288;
  const float* xr = x + (size_t)row * CC;
  float4 v = *(const float4*)(xr + tid * 4);
  *(float4*)(x2o + (size_t)row * CC + tid * 4) = v;  // seed x2 = x (Wo GEMM atomic-adds)
  float s  = v.x + v.y + v.z + v.w;
  float ss = v.x * v.x + v.y * v.y + v.z * v.z + v.w * v.w;
#pragma unroll
  for (int off = 32; off > 0; off >>= 1) {
    s  += __shfl_xor(s, off, 64);
    ss += __shfl_xor(ss, off, 64);
  }
  __shared__ float ls[4], lss[4];
  if ((tid & 63) == 0) { ls[tid >> 6] = s; lss[tid >> 6] = ss; }
  __syncthreads();
  s  = ls[0] + ls[1] + ls[2] + ls[3];
  ss = lss[0] + lss[1] + lss[2] + lss[3];
  const float mean = s * (1.0f / CC);
  const float var  = ss * (1.0f / CC) - mean * mean;
  const float rstd = rsqrtf(var + 1e-5f);
  float4 gv = *(const float4*)(g + tid * 4);
  float4 bv = *(const float4*)(bta + tid * 4);
  ushort4 o = make_ushort4(f2b((v.x - mean) * rstd * gv.x + bv.x),
                           f2b((v.y - mean) * rstd * gv.y + bv.y),
                           f2b((v.z - mean) * rstd * gv.z + bv.z),
                           f2b((v.w - mean) * rstd * gv.w + bv.w));
  *(ushort4*)(xlo + (size_t)row * CC + tid * 4) = o;
}

// ---------------- LayerNorm (fp32 in, bf16 out) + fp32 passthrough seed ----------------
// outc gets a copy of the fp32 input row (seeds `out` with x2 for the atomic split-K GEMM)
__global__ __launch_bounds__(256) void ln_kernel(const float* __restrict__ x,
                                                 const float* __restrict__ g,
                                                 const float* __restrict__ bta,
                                                 unsigned short* __restrict__ out,
                                                 float* __restrict__ outc) {
  const int row = blockIdx.x;
  const int tid = threadIdx.x;
  const float* xr = x + (size_t)row * CC;
  float4 v = *(const float4*)(xr + tid * 4);
  *(float4*)(outc + (size_t)row * CC + tid * 4) = v;  // seed out = x2
  float s  = v.x + v.y + v.z + v.w;
  float ss = v.x * v.x + v.y * v.y + v.z * v.z + v.w * v.w;
#pragma unroll
  for (int off = 32; off > 0; off >>= 1) {
    s  += __shfl_xor(s, off, 64);
    ss += __shfl_xor(ss, off, 64);
  }
  __shared__ float ls[4], lss[4];
  if ((tid & 63) == 0) { ls[tid >> 6] = s; lss[tid >> 6] = ss; }
  __syncthreads();
  s  = ls[0] + ls[1] + ls[2] + ls[3];
  ss = lss[0] + lss[1] + lss[2] + lss[3];
  const float mean = s * (1.0f / CC);
  const float var  = ss * (1.0f / CC) - mean * mean;
  const float rstd = rsqrtf(var + 1e-5f);
  float4 gv = *(const float4*)(g + tid * 4);
  float4 bv = *(const float4*)(bta + tid * 4);
  ushort4 o = make_ushort4(f2b((v.x - mean) * rstd * gv.x + bv.x),
                           f2b((v.y - mean) * rstd * gv.y + bv.y),
                           f2b((v.z - mean) * rstd * gv.z + bv.z),
                           f2b((v.w - mean) * rstd * gv.w + bv.w));
  *(ushort4*)(out + (size_t)row * CC + tid * 4) = o;
}

// ---------------- WKV hierarchical scan, 2 kernels ----------------
__global__ __launch_bounds__(64) void wkv_local(const unsigned short* __restrict__ kvr,
                                                const float* __restrict__ td,
                                                const float* __restrict__ tfp,
                                                float* __restrict__ scratch) {
  const int blk = blockIdx.x;
  const int bh = blk >> 5, c = blk & (NCH - 1);
  const int b = bh >> 4, h = bh & 15;
  const int s = threadIdx.x;
  const int ch = h * SS + s;
  const float e = __expf(td[ch]);
  const float d = __expf(-e);
  const float tfir = __expf(tfp[ch]);
  size_t idx = ((size_t)b * TT + (size_t)c * LCH) * KVRN + ch;
  float num = 0.f, den = 0.f;
  for (int i = 0; i < LCH; ++i) {
    float w = __expf(fminf(b2f(kvr[idx]), 30.f));
    if (c == 0 && i == 0) w *= tfir;  // time_first seeding at t==0
    float vv = b2f(kvr[idx + 1024]);
    num = d * num + w * vv;
    den = d * den + w;
    idx += KVRN;
  }
  float* o = scratch + ((size_t)bh * NCH + c) * 128;
  o[s] = num; o[64 + s] = den;
}

__global__ __launch_bounds__(64) void wkv_emit(const unsigned short* __restrict__ kvr,
                                               const float* __restrict__ td,
                                               const float* __restrict__ tfp,
                                               const float* __restrict__ scratch,
                                               unsigned short* __restrict__ rwkv) {
  const int blk = blockIdx.x;
  const int bh = blk >> 5, c = blk & (NCH - 1);
  const int b = bh >> 4, h = bh & 15;
  const int s = threadIdx.x;
  const int ch = h * SS + s;
  const float e = __expf(td[ch]);
  const float d = __expf(-e);
  const float Dc = __expf(-e * (float)LCH);
  const float tfir = __expf(tfp[ch]);
  float num = 0.f, den = 0.f;
  const float* sc = scratch + (size_t)bh * NCH * 128;
  for (int cc = 0; cc < c; ++cc) {
    num = Dc * num + sc[cc * 128 + s];
    den = Dc * den + sc[cc * 128 + 64 + s];
  }
  size_t idx = ((size_t)b * TT + (size_t)c * LCH) * KVRN + ch;
  size_t odx = ((size_t)b * TT + (size_t)c * LCH) * CC + ch;
  for (int i = 0; i < LCH; ++i) {
    float w = __expf(fminf(b2f(kvr[idx]), 30.f));
    if (c == 0 && i == 0) w *= tfir;
    float vv = b2f(kvr[idx + 1024]);
    num = d * num + w * vv;
    den = d * den + w;
    float o = num / (den + 1e-6f);
    float rr = b2f(kvr[idx + 2048]);
    float sg = 1.0f / (1.0f + __expf(-rr));
    rwkv[odx] = f2b(sg * o);
    idx += KVRN;
    odx += CC;
  }
}

// ---------------- bf16 MFMA GEMM: C[M,N] = A[M,Kslice] @ Bw[N,K]^T ----------------
// Round-0-proven structure, inner loop untouched: 128x128 tile, BK=32, 4 waves of 64x64,
// XOR-swizzled LDS (0 conflicts), gl_lds staging, 3 LDS buffers, prefetch distance 2,
// raw s_barrier preceded by s_waitcnt vmcnt(4). Only addition vs round-0: Kfull/Kloop
// split (Kfull = row stride, Kloop = this block's K extent, koff = blockIdx.y*Kloop)
// enabling split-K launches that raise resident blocks/CU from 2 to 3 on 512-block
// grids (Wo, Wffv) -- the only round-0 dispatches starved below 3 independent
// barrier-groups/CU. EP=0: bf16; EP=1: relu^2 bf16; EP=2: fp32 + res; EP=3: fp32
// unsafeAtomicAdd into pre-seeded output (mechanism + absmax proven rounds 1/2/3/5/6).
template <int EP>
__global__ __launch_bounds__(256, 3) void gemm_bt(const unsigned short* __restrict__ A,
                                                  const unsigned short* __restrict__ Bw,
                                                  void* __restrict__ outv,
                                                  const float* __restrict__ res,
                                                  int N, int Kfull, int Kloop) {
  __shared__ __align__(16) unsigned short As[3][128 * 32];
  __shared__ __align__(16) unsigned short Bs[3][128 * 32];
  const int tid = threadIdx.x;

  const int nbn = N >> 7;
  const int per_grp = nbn << 4;
  const int bid = blockIdx.x;
  const int grp = bid / per_grp;
  const int rem = bid - grp * per_grp;
  const int bm = (grp << 4) + (rem & 15);
  const int bn = rem >> 4;
  const int koff = blockIdx.y * Kloop;

  const int ch0 = tid, ch1 = tid + 256;
  const int r0 = ch0 >> 2, q0 = (ch0 & 3) ^ ((ch0 >> 3) & 3);
  const int r1 = ch1 >> 2, q1 = (ch1 & 3) ^ ((ch1 >> 3) & 3);
  const unsigned short* ga0 = A  + (size_t)(bm * 128 + r0) * Kfull + koff + q0 * 8;
  const unsigned short* ga1 = A  + (size_t)(bm * 128 + r1) * Kfull + koff + q1 * 8;
  const unsigned short* gb0 = Bw + (size_t)(bn * 128 + r0) * Kfull + koff + q0 * 8;
  const unsigned short* gb1 = Bw + (size_t)(bn * 128 + r1) * Kfull + koff + q1 * 8;
  const int so0 = ch0 * 8, so1 = ch1 * 8;

  const int lane = tid & 63;
  const int w    = tid >> 6;
  const int q    = lane >> 4, r16 = lane & 15;
  const int qs   = q ^ ((r16 >> 1) & 3);
  const int wrow = (w >> 1) * 64, wcol = (w & 1) * 64;

  f32x4 acc[4][4] = {};

  auto stage = [&](int b3) {
    gl_lds16(ga0, &As[b3][so0]);
    gl_lds16(ga1, &As[b3][so1]);
    gl_lds16(gb0, &Bs[b3][so0]);
    gl_lds16(gb1, &Bs[b3][so1]);
    ga0 += 32; ga1 += 32; gb0 += 32; gb1 += 32;
  };

  const int iters = Kloop >> 5;
  stage(0);
  stage(1);

  int cb = 0, pb = 2;
  for (int i = 0; i < iters; ++i) {
    __builtin_amdgcn_s_waitcnt(0x0F74);
    __builtin_amdgcn_sched_barrier(0);
    asm volatile("s_barrier");
    __builtin_amdgcn_sched_barrier(0);
    if (i + 2 < iters) stage(pb);

    const unsigned short* Ab = &As[cb][0];
    const unsigned short* Bb = &Bs[cb][0];
    short8 af[4], bfr[4];
#pragma unroll
    for (int mi = 0; mi < 4; ++mi)
      af[mi] = *(const short8*)(Ab + ((wrow + mi * 16 + r16) * 4 + qs) * 8);
#pragma unroll
    for (int ni = 0; ni < 4; ++ni)
      bfr[ni] = *(const short8*)(Bb + ((wcol + ni * 16 + r16) * 4 + qs) * 8);
#pragma unroll
    for (int mi = 0; mi < 4; ++mi)
#pragma unroll
      for (int ni = 0; ni < 4; ++ni)
        acc[mi][ni] = __builtin_amdgcn_mfma_f32_16x16x32_bf16(af[mi], bfr[ni], acc[mi][ni], 0, 0, 0);

    cb = (cb == 2) ? 0 : cb + 1;
    pb = (pb == 2) ? 0 : pb + 1;
  }

#pragma unroll
  for (int mi = 0; mi < 4; ++mi) {
#pragma unroll
    for (int r = 0; r < 4; ++r) {
      const int grow = bm * 128 + wrow + mi * 16 + q * 4 + r;
#pragma unroll
      for (int ni = 0; ni < 4; ++ni) {
        const int gcol = bn * 128 + wcol + ni * 16 + r16;
        const size_t idx = (size_t)grow * N + gcol;
        float vv = acc[mi][ni][r];
        if (EP == 2) {
          ((float*)outv)[idx] = res[idx] + vv;
        } else if (EP == 3) {
          unsafeAtomicAdd((float*)outv + idx, vv);
        } else {
          if (EP == 1) { vv = fmaxf(vv, 0.0f); vv = vv * vv; }
          ((unsigned short*)outv)[idx] = f2b(vv);
        }
      }
    }
  }
}

extern "C" void kernel_launch(void* const* d_in, const int* in_sizes, int n_in,
                              void* d_out, int out_size, void* d_ws, size_t ws_size,
                              hipStream_t stream) {
  const float* x    = (const float*)d_in[0];
  const float* td   = (const float*)d_in[1];
  const float* tf   = (const float*)d_in[2];
  const float* Wk   = (const float*)d_in[3];
  const float* Wv   = (const float*)d_in[4];
  const float* Wr   = (const float*)d_in[5];
  const float* Wo   = (const float*)d_in[6];
  const float* Wffk = (const float*)d_in[7];
  const float* Wffv = (const float*)d_in[8];
  const float* g1   = (const float*)d_in[9];
  const float* b1   = (const float*)d_in[10];
  const float* g2   = (const float*)d_in[11];
  const float* b2   = (const float*)d_in[12];
  float* out = (float*)d_out;

  char* ws = (char*)d_ws;
  const size_t MB = 1024ull * 1024ull;
  unsigned short* WB    = (unsigned short*)ws;              // 24 MB contiguous bf16 weights
  unsigned short* WkvrB = WB;                               // [3072,1024]
  unsigned short* WoB   = WB + 3 * 1048576;                 // [1024,1024]
  unsigned short* WfkB  = WB + 4 * 1048576;                 // [4096,1024]
  unsigned short* WfvB  = WB + 8 * 1048576;                 // [1024,4096]
  unsigned short* xl    = (unsigned short*)(ws + 24 * MB);  // 16 MB (reused as rwkv)
  unsigned short* kvr   = (unsigned short*)(ws + 40 * MB);  // 48 MB [8192,3072] (reused as xl2)
  float*          x2    = (float*)(ws + 88 * MB);           // 32 MB
  unsigned short* hb    = (unsigned short*)(ws + 120 * MB); // 64 MB
  float*          wkvS  = (float*)(ws + 184 * MB);          // 1 MB scan scratch -> total 185 MB
  unsigned short* rwkv  = xl;   // xl dead after kvr GEMM
  unsigned short* xl2   = kvr;  // kvr dead after wkv_emit

  // weights -> bf16 + LN1 + x2:=x seed, fused single launch
  cvt_ln_kernel<<<12288 + MROWS, 256, 0, stream>>>(Wk, Wv, Wr, Wo, Wffk, Wffv, WB,
                                                   x, g1, b1, xl, x2);

  // fused k|v|r GEMM: kvr[M,3072] = xl @ WkvrB^T   (1536 blocks = 3/CU, round-0 exact)
  gemm_bt<0><<<(KVRN / 128) * (MROWS / 128), 256, 0, stream>>>(
      xl, WkvrB, kvr, nullptr, KVRN, 1024, 1024);

  // WKV hierarchical scan + sigmoid(r) fuse
  wkv_local<<<64 * NCH, 64, 0, stream>>>(kvr, td, tf, wkvS);
  wkv_emit<<<64 * NCH, 64, 0, stream>>>(kvr, td, tf, wkvS, rwkv);

  // x2 += rwkv @ Wo^T  (x2 pre-seeded with x; split-K x2 -> 1024 blocks = 3/CU resident)
  gemm_bt<3><<<dim3((CC / 128) * (MROWS / 128), 2), 256, 0, stream>>>(
      rwkv, WoB, x2, nullptr, CC, 1024, 512);

  // LN2 (+ seed out = x2 for the atomic split-K Wffv below)
  ln_kernel<<<MROWS, 256, 0, stream>>>(x2, g2, b2, xl2, out);

  // h = relu(xl2 @ Wffk^T)^2   (2048 blocks, round-0 exact)
  gemm_bt<1><<<(4096 / 128) * (MROWS / 128), 256, 0, stream>>>(
      xl2, WfkB, hb, nullptr, 4096, 1024, 1024);

  // out += h @ Wffv^T   (split-K x2: 2x512 blocks = 3/CU resident, K=2048 each)
  gemm_bt<3><<<dim3((CC / 128) * (MROWS / 128), 2), 256, 0, stream>>>(
      hb, WfvB, out, nullptr, CC, 4096, 2048);
}

// Round 8
// 440.321 us; speedup vs baseline: 1.2110x; 1.2110x over previous
//
#include <hip/hip_runtime.h>
#include <cstdint>
#include <cstddef>

// Problem constants (B=4, T=2048, C=1024, H=16, S=64)
#define TT 2048
#define CC 1024
#define HH 16
#define SS 64
#define MROWS 8192  // B*T
#define KVRN 3072   // fused k|v|r width
#define NCH 32      // WKV chunks per sequence
#define LCH 64      // steps per chunk (TT/NCH)

using short8 = __attribute__((ext_vector_type(8))) short;
using f32x4  = __attribute__((ext_vector_type(4))) float;

__device__ __forceinline__ float b2f(unsigned short u) {
  union { unsigned int i; float f; } c; c.i = ((unsigned int)u) << 16; return c.f;
}
__device__ __forceinline__ unsigned short f2b(float f) {
  union { float f; unsigned int i; } c; c.f = f;
  unsigned int r = c.i + 0x7fffu + ((c.i >> 16) & 1u);  // RNE; inputs finite
  return (unsigned short)(r >> 16);
}

// async global->LDS, 16 bytes per lane (LDS dst = wave-uniform base + lane*16; global per-lane)
typedef const __attribute__((address_space(1))) unsigned int* gas_ptr;
typedef __attribute__((address_space(3))) unsigned int* las_ptr;
__device__ __forceinline__ void gl_lds16(const unsigned short* g, unsigned short* l) {
  __builtin_amdgcn_global_load_lds((gas_ptr)g, (las_ptr)l, 16, 0, 0);
}

// ---------------- fused: all weights fp32->bf16 + LN1, one launch ----------------
// blocks [0,12288): cvt; blocks [12288,20480): LN1 row (blockIdx-12288)
__global__ __launch_bounds__(256) void cvt_ln_kernel(const float* __restrict__ Wk,
                                                     const float* __restrict__ Wv,
                                                     const float* __restrict__ Wr,
                                                     const float* __restrict__ Wo,
                                                     const float* __restrict__ Wffk,
                                                     const float* __restrict__ Wffv,
                                                     unsigned short* __restrict__ dst,
                                                     const float* __restrict__ x,
                                                     const float* __restrict__ g,
                                                     const float* __restrict__ bta,
                                                     unsigned short* __restrict__ xlo) {
  const size_t M1 = 1048576;
  const int tid = threadIdx.x;
  if (blockIdx.x < 12288) {
    size_t i = ((size_t)blockIdx.x * 256 + tid) * 4;
    const float* src; size_t off;
    if      (i <  1 * M1) { src = Wk;   off = 0;      }
    else if (i <  2 * M1) { src = Wv;   off = 1 * M1; }
    else if (i <  3 * M1) { src = Wr;   off = 2 * M1; }
    else if (i <  4 * M1) { src = Wo;   off = 3 * M1; }
    else if (i <  8 * M1) { src = Wffk; off = 4 * M1; }
    else                  { src = Wffv; off = 8 * M1; }
    float4 v = *(const float4*)(src + (i - off));
    *(ushort4*)(dst + i) = make_ushort4(f2b(v.x), f2b(v.y), f2b(v.z), f2b(v.w));
    return;
  }
  const int row = blockIdx.x - 12288;
  const float* xr = x + (size_t)row * CC;
  float4 v = *(const float4*)(xr + tid * 4);
  float s  = v.x + v.y + v.z + v.w;
  float ss = v.x * v.x + v.y * v.y + v.z * v.z + v.w * v.w;
#pragma unroll
  for (int off = 32; off > 0; off >>= 1) {
    s  += __shfl_xor(s, off, 64);
    ss += __shfl_xor(ss, off, 64);
  }
  __shared__ float ls[4], lss[4];
  if ((tid & 63) == 0) { ls[tid >> 6] = s; lss[tid >> 6] = ss; }
  __syncthreads();
  s  = ls[0] + ls[1] + ls[2] + ls[3];
  ss = lss[0] + lss[1] + lss[2] + lss[3];
  const float mean = s * (1.0f / CC);
  const float var  = ss * (1.0f / CC) - mean * mean;
  const float rstd = rsqrtf(var + 1e-5f);
  float4 gv = *(const float4*)(g + tid * 4);
  float4 bv = *(const float4*)(bta + tid * 4);
  ushort4 o = make_ushort4(f2b((v.x - mean) * rstd * gv.x + bv.x),
                           f2b((v.y - mean) * rstd * gv.y + bv.y),
                           f2b((v.z - mean) * rstd * gv.z + bv.z),
                           f2b((v.w - mean) * rstd * gv.w + bv.w));
  *(ushort4*)(xlo + (size_t)row * CC + tid * 4) = o;
}

// ---------------- LayerNorm (fp32 in, bf16 out), one block per row ----------------
__global__ __launch_bounds__(256) void ln_kernel(const float* __restrict__ x,
                                                 const float* __restrict__ g,
                                                 const float* __restrict__ bta,
                                                 unsigned short* __restrict__ out) {
  const int row = blockIdx.x;
  const int tid = threadIdx.x;
  const float* xr = x + (size_t)row * CC;
  float4 v = *(const float4*)(xr + tid * 4);
  float s  = v.x + v.y + v.z + v.w;
  float ss = v.x * v.x + v.y * v.y + v.z * v.z + v.w * v.w;
#pragma unroll
  for (int off = 32; off > 0; off >>= 1) {
    s  += __shfl_xor(s, off, 64);
    ss += __shfl_xor(ss, off, 64);
  }
  __shared__ float ls[4], lss[4];
  if ((tid & 63) == 0) { ls[tid >> 6] = s; lss[tid >> 6] = ss; }
  __syncthreads();
  s  = ls[0] + ls[1] + ls[2] + ls[3];
  ss = lss[0] + lss[1] + lss[2] + lss[3];
  const float mean = s * (1.0f / CC);
  const float var  = ss * (1.0f / CC) - mean * mean;
  const float rstd = rsqrtf(var + 1e-5f);
  float4 gv = *(const float4*)(g + tid * 4);
  float4 bv = *(const float4*)(bta + tid * 4);
  ushort4 o = make_ushort4(f2b((v.x - mean) * rstd * gv.x + bv.x),
                           f2b((v.y - mean) * rstd * gv.y + bv.y),
                           f2b((v.z - mean) * rstd * gv.z + bv.z),
                           f2b((v.w - mean) * rstd * gv.w + bv.w));
  *(ushort4*)(out + (size_t)row * CC + tid * 4) = o;
}

// ---------------- WKV hierarchical scan, 2 kernels ----------------
__global__ __launch_bounds__(64) void wkv_local(const unsigned short* __restrict__ kvr,
                                                const float* __restrict__ td,
                                                const float* __restrict__ tfp,
                                                float* __restrict__ scratch) {
  const int blk = blockIdx.x;
  const int bh = blk >> 5, c = blk & (NCH - 1);
  const int b = bh >> 4, h = bh & 15;
  const int s = threadIdx.x;
  const int ch = h * SS + s;
  const float e = __expf(td[ch]);
  const float d = __expf(-e);
  const float tfir = __expf(tfp[ch]);
  size_t idx = ((size_t)b * TT + (size_t)c * LCH) * KVRN + ch;
  float num = 0.f, den = 0.f;
  for (int i = 0; i < LCH; ++i) {
    float w = __expf(fminf(b2f(kvr[idx]), 30.f));
    if (c == 0 && i == 0) w *= tfir;  // time_first seeding at t==0
    float vv = b2f(kvr[idx + 1024]);
    num = d * num + w * vv;
    den = d * den + w;
    idx += KVRN;
  }
  float* o = scratch + ((size_t)bh * NCH + c) * 128;
  o[s] = num; o[64 + s] = den;
}

__global__ __launch_bounds__(64) void wkv_emit(const unsigned short* __restrict__ kvr,
                                               const float* __restrict__ td,
                                               const float* __restrict__ tfp,
                                               const float* __restrict__ scratch,
                                               unsigned short* __restrict__ rwkv) {
  const int blk = blockIdx.x;
  const int bh = blk >> 5, c = blk & (NCH - 1);
  const int b = bh >> 4, h = bh & 15;
  const int s = threadIdx.x;
  const int ch = h * SS + s;
  const float e = __expf(td[ch]);
  const float d = __expf(-e);
  const float Dc = __expf(-e * (float)LCH);
  const float tfir = __expf(tfp[ch]);
  float num = 0.f, den = 0.f;
  const float* sc = scratch + (size_t)bh * NCH * 128;
  for (int cc = 0; cc < c; ++cc) {
    num = Dc * num + sc[cc * 128 + s];
    den = Dc * den + sc[cc * 128 + 64 + s];
  }
  size_t idx = ((size_t)b * TT + (size_t)c * LCH) * KVRN + ch;
  size_t odx = ((size_t)b * TT + (size_t)c * LCH) * CC + ch;
  for (int i = 0; i < LCH; ++i) {
    float w = __expf(fminf(b2f(kvr[idx]), 30.f));
    if (c == 0 && i == 0) w *= tfir;
    float vv = b2f(kvr[idx + 1024]);
    num = d * num + w * vv;
    den = d * den + w;
    float o = num / (den + 1e-6f);
    float rr = b2f(kvr[idx + 2048]);
    float sg = 1.0f / (1.0f + __expf(-rr));
    rwkv[odx] = f2b(sg * o);
    idx += KVRN;
    odx += CC;
  }
}

// ---------------- bf16 MFMA GEMM: C[M,N] = A[M,K] @ Bw[N,K]^T ----------------
// 128x128 tile, BK=32, 4 waves of 64x64, XOR-swizzled LDS (0 conflicts), gl_lds staging.
// AITER-style K-loop: 3 LDS buffers, prefetch distance 2, RAW s_barrier (inline asm, no
// compiler vmcnt(0) drain) preceded by explicit s_waitcnt vmcnt(4). Each wave has <=8
// gl_lds outstanding; vmcnt(4) waits only the 4 oldest (= tile i, in-order completion),
// leaving the newer prefetches in flight ACROSS the barrier. Every wave performs the
// same wait before the barrier, so after barrier-release tile i is fully in LDS.
// ds_reads of tile i-1 are consumed by MFMAs (lgkm-waited) before a wave reaches the
// next barrier, so buffer reuse (i+2 overwrites i-1's buffer) is race-free.
// 1-D grid, M-grouped (16 bm per group) for L2 reuse of B tiles.
// EP=0: bf16 store; EP=1: relu^2 -> bf16; EP=2: fp32 store with residual add
template <int EP>
__global__ __launch_bounds__(256, 3) void gemm_bt(const unsigned short* __restrict__ A,
                                                  const unsigned short* __restrict__ Bw,
                                                  void* __restrict__ outv,
                                                  const float* __restrict__ res,
                                                  int N, int K) {
  __shared__ __align__(16) unsigned short As[3][128 * 32];
  __shared__ __align__(16) unsigned short Bs[3][128 * 32];
  const int tid = threadIdx.x;

  // grid decode: groups of 16 bm-tiles sweep all bn for L2 reuse
  const int nbn = N >> 7;
  const int per_grp = nbn << 4;
  const int bid = blockIdx.x;
  const int grp = bid / per_grp;
  const int rem = bid - grp * per_grp;
  const int bm = (grp << 4) + (rem & 15);
  const int bn = rem >> 4;

  // staging: 512 16B chunks per tile; thread stages chunks tid and tid+256 for A and B.
  // chunk i holds global (row = i>>2, kgroup = (i&3) ^ ((i>>3)&3)); LDS dst = base + i*16.
  const int ch0 = tid, ch1 = tid + 256;
  const int r0 = ch0 >> 2, q0 = (ch0 & 3) ^ ((ch0 >> 3) & 3);
  const int r1 = ch1 >> 2, q1 = (ch1 & 3) ^ ((ch1 >> 3) & 3);
  const unsigned short* ga0 = A  + (size_t)(bm * 128 + r0) * K + q0 * 8;
  const unsigned short* ga1 = A  + (size_t)(bm * 128 + r1) * K + q1 * 8;
  const unsigned short* gb0 = Bw + (size_t)(bn * 128 + r0) * K + q0 * 8;
  const unsigned short* gb1 = Bw + (size_t)(bn * 128 + r1) * K + q1 * 8;
  const int so0 = ch0 * 8, so1 = ch1 * 8;

  const int lane = tid & 63;
  const int w    = tid >> 6;
  const int q    = lane >> 4, r16 = lane & 15;
  const int qs   = q ^ ((r16 >> 1) & 3);  // swizzled k-group for frag reads
  const int wrow = (w >> 1) * 64, wcol = (w & 1) * 64;

  f32x4 acc[4][4] = {};

  auto stage = [&](int b3) {
    gl_lds16(ga0, &As[b3][so0]);
    gl_lds16(ga1, &As[b3][so1]);
    gl_lds16(gb0, &Bs[b3][so0]);
    gl_lds16(gb1, &Bs[b3][so1]);
    ga0 += 32; ga1 += 32; gb0 += 32; gb1 += 32;
  };

  const int iters = K >> 5;  // >= 32 always here
  // prologue: tiles 0,1 into buffers 0,1 (8 gl_lds outstanding per wave)
  stage(0);
  stage(1);

  int cb = 0, pb = 2;
  for (int i = 0; i < iters; ++i) {
    // wait this wave's 4 oldest loads (tile i) -> landed; newer 4 stay in flight.
    // imm 0xF74: vmcnt=4, expcnt=7 (none), lgkmcnt=15 (none)
    __builtin_amdgcn_s_waitcnt(0x0F74);
    __builtin_amdgcn_sched_barrier(0);
    asm volatile("s_barrier");          // raw barrier: NO vmcnt(0) drain
    __builtin_amdgcn_sched_barrier(0);
    if (i + 2 < iters) stage(pb);       // tile i+2: in flight for ~2 compute phases

    const unsigned short* Ab = &As[cb][0];
    const unsigned short* Bb = &Bs[cb][0];
    short8 af[4], bfr[4];
#pragma unroll
    for (int mi = 0; mi < 4; ++mi)
      af[mi] = *(const short8*)(Ab + ((wrow + mi * 16 + r16) * 4 + qs) * 8);
#pragma unroll
    for (int ni = 0; ni < 4; ++ni)
      bfr[ni] = *(const short8*)(Bb + ((wcol + ni * 16 + r16) * 4 + qs) * 8);
#pragma unroll
    for (int mi = 0; mi < 4; ++mi)
#pragma unroll
      for (int ni = 0; ni < 4; ++ni)
        acc[mi][ni] = __builtin_amdgcn_mfma_f32_16x16x32_bf16(af[mi], bfr[ni], acc[mi][ni], 0, 0, 0);

    cb = (cb == 2) ? 0 : cb + 1;
    pb = (pb == 2) ? 0 : pb + 1;
  }

  // epilogue: D[m = quad*4+reg][n = lane&15]
#pragma unroll
  for (int mi = 0; mi < 4; ++mi) {
#pragma unroll
    for (int r = 0; r < 4; ++r) {
      const int grow = bm * 128 + wrow + mi * 16 + q * 4 + r;
#pragma unroll
      for (int ni = 0; ni < 4; ++ni) {
        const int gcol = bn * 128 + wcol + ni * 16 + r16;
        const size_t idx = (size_t)grow * N + gcol;
        float vv = acc[mi][ni][r];
        if (EP == 2) {
          ((float*)outv)[idx] = res[idx] + vv;
        } else {
          if (EP == 1) { vv = fmaxf(vv, 0.0f); vv = vv * vv; }
          ((unsigned short*)outv)[idx] = f2b(vv);
        }
      }
    }
  }
}

extern "C" void kernel_launch(void* const* d_in, const int* in_sizes, int n_in,
                              void* d_out, int out_size, void* d_ws, size_t ws_size,
                              hipStream_t stream) {
  const float* x    = (const float*)d_in[0];
  const float* td   = (const float*)d_in[1];
  const float* tf   = (const float*)d_in[2];
  const float* Wk   = (const float*)d_in[3];
  const float* Wv   = (const float*)d_in[4];
  const float* Wr   = (const float*)d_in[5];
  const float* Wo   = (const float*)d_in[6];
  const float* Wffk = (const float*)d_in[7];
  const float* Wffv = (const float*)d_in[8];
  const float* g1   = (const float*)d_in[9];
  const float* b1   = (const float*)d_in[10];
  const float* g2   = (const float*)d_in[11];
  const float* b2   = (const float*)d_in[12];
  float* out = (float*)d_out;

  char* ws = (char*)d_ws;
  const size_t MB = 1024ull * 1024ull;
  unsigned short* WB    = (unsigned short*)ws;              // 24 MB contiguous bf16 weights
  unsigned short* WkvrB = WB;                               // [3072,1024]
  unsigned short* WoB   = WB + 3 * 1048576;                 // [1024,1024]
  unsigned short* WfkB  = WB + 4 * 1048576;                 // [4096,1024]
  unsigned short* WfvB  = WB + 8 * 1048576;                 // [1024,4096]
  unsigned short* xl    = (unsigned short*)(ws + 24 * MB);  // 16 MB (reused as rwkv)
  unsigned short* kvr   = (unsigned short*)(ws + 40 * MB);  // 48 MB [8192,3072] (reused as xl2)
  float*          x2    = (float*)(ws + 88 * MB);           // 32 MB
  unsigned short* hb    = (unsigned short*)(ws + 120 * MB); // 64 MB
  float*          wkvS  = (float*)(ws + 184 * MB);          // 1 MB scan scratch -> total 185 MB
  unsigned short* rwkv  = xl;   // xl dead after kvr GEMM
  unsigned short* xl2   = kvr;  // kvr dead after wkv_emit

  // weights -> bf16 + LN1, fused single launch
  cvt_ln_kernel<<<12288 + MROWS, 256, 0, stream>>>(Wk, Wv, Wr, Wo, Wffk, Wffv, WB,
                                                   x, g1, b1, xl);

  // fused k|v|r GEMM: kvr[M,3072] = xl @ WkvrB^T   (1536 blocks)
  gemm_bt<0><<<(KVRN / 128) * (MROWS / 128), 256, 0, stream>>>(xl, WkvrB, kvr, nullptr, KVRN, 1024);

  // WKV hierarchical scan + sigmoid(r) fuse
  wkv_local<<<64 * NCH, 64, 0, stream>>>(kvr, td, tf, wkvS);
  wkv_emit<<<64 * NCH, 64, 0, stream>>>(kvr, td, tf, wkvS, rwkv);

  // x2 = x + rwkv @ Wo^T   (512 blocks)
  gemm_bt<2><<<(CC / 128) * (MROWS / 128), 256, 0, stream>>>(rwkv, WoB, x2, x, 1024, 1024);

  // LN2
  ln_kernel<<<MROWS, 256, 0, stream>>>(x2, g2, b2, xl2);

  // h = relu(xl2 @ Wffk^T)^2   (2048 blocks)
  gemm_bt<1><<<(4096 / 128) * (MROWS / 128), 256, 0, stream>>>(xl2, WfkB, hb, nullptr, 4096, 1024);

  // out = x2 + h @ Wffv^T   (512 blocks, K=4096)
  gemm_bt<2><<<(CC / 128) * (MROWS / 128), 256, 0, stream>>>(hb, WfvB, out, x2, 1024, 4096);
}